// Round 4
// baseline (415.253 us; speedup 1.0000x reference)
//
#include <hip/hip_runtime.h>

#define B_SZ 32768
#define I_SZ 256
#define H_SZ 512
#define K_SZ 768   // I + H
#define NG   2048  // 4*H

typedef _Float16 half8 __attribute__((ext_vector_type(8)));
typedef _Float16 half4v __attribute__((ext_vector_type(4)));
typedef float f32x4 __attribute__((ext_vector_type(4)));

__device__ __forceinline__ float sigf(float x) {
  return __builtin_amdgcn_rcpf(1.0f + __builtin_amdgcn_exp2f(-1.44269504089f * x));
}
__device__ __forceinline__ float tanh_fast(float x) {
  return 1.0f - 2.0f * __builtin_amdgcn_rcpf(1.0f + __builtin_amdgcn_exp2f(2.88539008178f * x));
}

__device__ __forceinline__ void gl2lds16(const void* g, void* l) {
  __builtin_amdgcn_global_load_lds(
      (const __attribute__((address_space(1))) void*)g,
      (__attribute__((address_space(3))) void*)l, 16, 0, 0);
}

// ---------------- fused pre-pass (4 rows per 256-thread block, 1 wave/row) ----
// blocks [0, B_SZ/4)                : A rows (f16 row-major [x|h])
// blocks [B_SZ/4, B_SZ/4+NG/4)     : W rows -> MFMA-fragment order
// last block                        : bias sum
__global__ void __launch_bounds__(256) prepass(const float* __restrict__ x,
                                               const float* __restrict__ h,
                                               const float* __restrict__ Wx,
                                               const float* __restrict__ Wh,
                                               const float* __restrict__ bx,
                                               const float* __restrict__ bh,
                                               _Float16* __restrict__ Aw,
                                               _Float16* __restrict__ Wf,
                                               float* __restrict__ bs) {
  const int t = threadIdx.x;
  const int w = t >> 6, l = t & 63;
  const int bid = blockIdx.x;
  const int NA = B_SZ / 4;          // 8192
  const int NW = NG / 4;            // 512
  if (bid < NA) {
    const int r = bid * 4 + w;
    float4 vx = *(const float4*)(x + (size_t)r * I_SZ + l * 4);
    float4 v1 = *(const float4*)(h + (size_t)r * H_SZ + l * 4);
    float4 v2 = *(const float4*)(h + (size_t)r * H_SZ + 256 + l * 4);
    _Float16* dst = Aw + (size_t)r * K_SZ;
    half4v o0 = {(_Float16)vx.x, (_Float16)vx.y, (_Float16)vx.z, (_Float16)vx.w};
    half4v o1 = {(_Float16)v1.x, (_Float16)v1.y, (_Float16)v1.z, (_Float16)v1.w};
    half4v o2 = {(_Float16)v2.x, (_Float16)v2.y, (_Float16)v2.z, (_Float16)v2.w};
    *(half4v*)(dst + l * 4) = o0;
    *(half4v*)(dst + 256 + l * 4) = o1;
    *(half4v*)(dst + 512 + l * 4) = o2;
  } else if (bid < NA + NW) {
    const int r = (bid - NA) * 4 + w;   // Ww row = gate*512 + j
    const int g = r >> 9, j = r & 511;
    const int nb = j >> 5, jl = j & 31;
    const int cc = jl * 4 + g;          // tile col within 128-col block
    const int wc = cc >> 6, ni = (cc >> 4) & 3, l15 = cc & 15;
#pragma unroll
    for (int seg = 0; seg < 3; ++seg) {
      const int k = seg * 256 + l * 4;
      float4 v;
      if (seg == 0) v = *(const float4*)(Wx + (size_t)r * I_SZ + k);
      else          v = *(const float4*)(Wh + (size_t)r * H_SZ + (k - 256));
      const int kb = k >> 6, ks = (k >> 5) & 1, l4 = (k >> 3) & 3, e = k & 7;
      const int f = (((nb * 2 + wc) * 12 + kb) * 2 + ks) * 4 + ni;
      half4v o = {(_Float16)v.x, (_Float16)v.y, (_Float16)v.z, (_Float16)v.w};
      *(half4v*)(Wf + (size_t)f * 512 + (l4 * 16 + l15) * 8 + e) = o;
    }
  } else {
#pragma unroll
    for (int q = 0; q < NG / 256; ++q) bs[q * 256 + t] = bx[q * 256 + t] + bh[q * 256 + t];
  }
}

// ---------------- main fused GEMM + LSTM epilogue ----------------
// 128x128 block tile, 4 waves 2x2, 16x16x32 f16 MFMA, BK=64.
// A: LDS double buffer, XOR swizzle, global_load_lds w16, one barrier/iter.
// W: fragment-ordered global loads, REGISTER double-buffered one kb ahead.
// XCD swizzle: the 16 blocks sharing an A panel land on one XCD's L2.
__global__ void __launch_bounds__(256) lstm_gemm(const _Float16* __restrict__ Aw,
                                                 const _Float16* __restrict__ Wf,
                                                 const float* __restrict__ bs,
                                                 const float* __restrict__ cIn,
                                                 float* __restrict__ outc,
                                                 float* __restrict__ outh) {
  __shared__ __align__(16) char smem[32768];

  const int t = threadIdx.x;
  const int lane = t & 63;
  const int wave = t >> 6;
  const int wr = wave >> 1, wc = wave & 1;
  const int l15 = lane & 15, l4 = lane >> 4;
  const int sw = l15 & 7;

  // XCD-aware: consecutive dispatch chunk of 128 bids = 8 XCDs x 16 nb;
  // same-XCD members (bid mod 8 equal) share mb -> A panel stays in one L2.
  const int bid = blockIdx.x;
  const int mb = (bid & 7) + (bid >> 7) * 8;
  const int nb = (bid >> 3) & 15;
  const int j0 = nb * 32;
  const int m0 = mb * 128;

  const int rA = t >> 3;
  const int colb = ((t & 7) ^ (rA & 7)) * 8;
  const size_t aBase = (size_t)(m0 + rA) * K_SZ + colb;

  const _Float16* wBase = Wf + (size_t)(nb * 2 + wc) * 96 * 512 + lane * 8;

  // init accumulators with bias
  f32x4 acc[4][4];
#pragma unroll
  for (int ni = 0; ni < 4; ++ni) {
    int tcol = wc * 64 + ni * 16 + l15;
    int gcol = (tcol & 3) * H_SZ + j0 + (tcol >> 2);
    float b = bs[gcol];
    f32x4 v = {b, b, b, b};
#pragma unroll
    for (int mi = 0; mi < 4; ++mi) acc[mi][ni] = v;
  }

  // prologue: stage A kb=0 into buf0; preload W kb=0 into regs
#pragma unroll
  for (int q = 0; q < 4; ++q)
    gl2lds16(Aw + aBase + (size_t)q * 32 * K_SZ, smem + t * 16 + q * 4096);

  half8 wA[8], wB[8];
#pragma unroll
  for (int f = 0; f < 8; ++f) wA[f] = *(const half8*)(wBase + (size_t)f * 512);

  auto kstep = [&](int kb, half8 (&wcur)[8], half8 (&wnxt)[8]) {
    __syncthreads();   // drains stage(kb) issued one iter ago (nearly free)
    if (kb < K_SZ / 64 - 1) {
      char* ldsNext = smem + ((kb + 1) & 1) * 16384 + t * 16;
#pragma unroll
      for (int q = 0; q < 4; ++q)
        gl2lds16(Aw + aBase + (size_t)q * 32 * K_SZ + (size_t)(kb + 1) * 64,
                 ldsNext + q * 4096);
#pragma unroll
      for (int f = 0; f < 8; ++f)
        wnxt[f] = *(const half8*)(wBase + (size_t)((kb + 1) * 8 + f) * 512);
    }
    const _Float16* As = (const _Float16*)(smem + (kb & 1) * 16384);
#pragma unroll
    for (int ks = 0; ks < 2; ++ks) {
      half8 af[4];
#pragma unroll
      for (int mi = 0; mi < 4; ++mi)
        af[mi] = *(const half8*)(As + (wr * 64 + mi * 16 + l15) * 64 + (((ks * 4 + l4) ^ sw) * 8));
#pragma unroll
      for (int mi = 0; mi < 4; ++mi)
#pragma unroll
        for (int ni = 0; ni < 4; ++ni)
          acc[mi][ni] = __builtin_amdgcn_mfma_f32_16x16x32_f16(af[mi], wcur[ks * 4 + ni], acc[mi][ni], 0, 0, 0);
    }
  };

#pragma unroll
  for (int kb = 0; kb < K_SZ / 64; kb += 2) {
    kstep(kb, wA, wB);
    kstep(kb + 1, wB, wA);
  }
  __syncthreads();

  // ---- epilogue: per-wave LDS transpose (stride 68 floats) ----
  float* T = (float*)(smem + wave * 8192);
#pragma unroll
  for (int mi = 0; mi < 4; ++mi) {
#pragma unroll
    for (int ni = 0; ni < 4; ++ni)
#pragma unroll
      for (int r = 0; r < 4; ++r)
        T[(l4 * 4 + r) * 68 + ni * 16 + l15] = acc[mi][ni][r];
#pragma unroll
    for (int orow = 0; orow < 4; ++orow) {
      int rloc = orow * 4 + l4;
      f32x4 gv = *(const f32x4*)(T + rloc * 68 + l15 * 4);
      int rowg = m0 + wr * 64 + mi * 16 + rloc;
      int jg = j0 + wc * 16 + l15;
      size_t off = (size_t)rowg * H_SZ + jg;
      float cv = cIn[off];
      float it = sigf(gv[0]);
      float ft = sigf(gv[1]);
      float ot = sigf(gv[2]);
      float tc = tanh_fast(gv[3]);
      float ct = ft * cv + it * tc;
      float ht = ot * tanh_fast(ct);
      outc[off] = ct;
      outh[off] = ht;
    }
  }
}

// ---------------- fallback (ws too small): plain fp32 ----------------
__global__ void __launch_bounds__(256) lstm_naive(const float* __restrict__ x,
                                                  const float* __restrict__ h,
                                                  const float* __restrict__ c,
                                                  const float* __restrict__ Wx,
                                                  const float* __restrict__ bx,
                                                  const float* __restrict__ Wh,
                                                  const float* __restrict__ bh,
                                                  float* __restrict__ outc,
                                                  float* __restrict__ outh) {
  int idx = blockIdx.x * 256 + threadIdx.x;
  int b = idx >> 9, j = idx & 511;
  float gi = bx[j] + bh[j];
  float gf = bx[H_SZ + j] + bh[H_SZ + j];
  float go = bx[2 * H_SZ + j] + bh[2 * H_SZ + j];
  float gc = bx[3 * H_SZ + j] + bh[3 * H_SZ + j];
  const float* xr = x + (size_t)b * I_SZ;
  for (int k = 0; k < I_SZ; ++k) {
    float xv = xr[k];
    gi += xv * Wx[(size_t)j * I_SZ + k];
    gf += xv * Wx[(size_t)(H_SZ + j) * I_SZ + k];
    go += xv * Wx[(size_t)(2 * H_SZ + j) * I_SZ + k];
    gc += xv * Wx[(size_t)(3 * H_SZ + j) * I_SZ + k];
  }
  const float* hr = h + (size_t)b * H_SZ;
  for (int k = 0; k < H_SZ; ++k) {
    float hv = hr[k];
    gi += hv * Wh[(size_t)j * H_SZ + k];
    gf += hv * Wh[(size_t)(H_SZ + j) * H_SZ + k];
    go += hv * Wh[(size_t)(2 * H_SZ + j) * H_SZ + k];
    gc += hv * Wh[(size_t)(3 * H_SZ + j) * H_SZ + k];
  }
  float it = sigf(gi), ft = sigf(gf), ot = sigf(go), tc = tanh_fast(gc);
  float ct = ft * c[idx] + it * tc;
  outc[idx] = ct;
  outh[idx] = ot * tanh_fast(ct);
}

extern "C" void kernel_launch(void* const* d_in, const int* in_sizes, int n_in,
                              void* d_out, int out_size, void* d_ws, size_t ws_size,
                              hipStream_t stream) {
  const float* x  = (const float*)d_in[0];
  const float* h  = (const float*)d_in[1];
  const float* c  = (const float*)d_in[2];
  const float* Wx = (const float*)d_in[3];
  const float* bx = (const float*)d_in[4];
  const float* Wh = (const float*)d_in[5];
  const float* bh = (const float*)d_in[6];
  float* outc = (float*)d_out;
  float* outh = outc + (size_t)B_SZ * H_SZ;

  const size_t szA = (size_t)B_SZ * K_SZ * sizeof(_Float16);
  const size_t szW = (size_t)NG * K_SZ * sizeof(_Float16);
  const size_t need = szA + szW + (size_t)NG * sizeof(float);

  if (ws_size < need) {
    lstm_naive<<<(B_SZ * H_SZ) / 256, 256, 0, stream>>>(x, h, c, Wx, bx, Wh, bh, outc, outh);
    return;
  }

  _Float16* Aw = (_Float16*)d_ws;
  _Float16* Wf = (_Float16*)((char*)d_ws + szA);
  float* bs = (float*)((char*)d_ws + szA + szW);

  prepass<<<B_SZ / 4 + NG / 4 + 1, 256, 0, stream>>>(x, h, Wx, Wh, bx, bh, Aw, Wf, bs);
  lstm_gemm<<<(B_SZ / 128) * (NG / 128), 256, 0, stream>>>(Aw, Wf, bs, c, outc, outh);
}

// Round 5
// 396.992 us; speedup vs baseline: 1.0460x; 1.0460x over previous
//
#include <hip/hip_runtime.h>

#define B_SZ 32768
#define I_SZ 256
#define H_SZ 512
#define K_SZ 768   // I + H
#define NG   2048  // 4*H

typedef _Float16 half8 __attribute__((ext_vector_type(8)));
typedef _Float16 half4v __attribute__((ext_vector_type(4)));
typedef float f32x4 __attribute__((ext_vector_type(4)));

__device__ __forceinline__ float sigf(float x) {
  return __builtin_amdgcn_rcpf(1.0f + __builtin_amdgcn_exp2f(-1.44269504089f * x));
}
__device__ __forceinline__ float tanh_fast(float x) {
  return 1.0f - 2.0f * __builtin_amdgcn_rcpf(1.0f + __builtin_amdgcn_exp2f(2.88539008178f * x));
}

// ---------------- fused pre-pass: cast fp32->f16, BOTH A and W into MFMA-fragment order ----
// A frag addressing (f16 elems):  mb*98304 + kb*8192 + ks*4096 + wr*2048 + mi*512 + lane*8
//   (row r: mb=r>>7, lr=r&127 -> wr=lr>>6, mi=(lr>>4)&3, rr=lr&15; lane=(k>>3&3)*16+rr)
// W frag addressing:  (nb*2+wc)*49152 + (kb*8+ks*4+ni)*512 + lane*8
// blocks [0, B_SZ/4): A rows (4/block, 1 wave each); next NG/4: W rows; last: bias.
__global__ void __launch_bounds__(256) prepass(const float* __restrict__ x,
                                               const float* __restrict__ h,
                                               const float* __restrict__ Wx,
                                               const float* __restrict__ Wh,
                                               const float* __restrict__ bx,
                                               const float* __restrict__ bh,
                                               _Float16* __restrict__ Af,
                                               _Float16* __restrict__ Wf,
                                               float* __restrict__ bs) {
  const int t = threadIdx.x;
  const int w = t >> 6, l = t & 63;
  const int bid = blockIdx.x;
  const int NA = B_SZ / 4;          // 8192
  const int NW = NG / 4;            // 512
  if (bid < NA) {
    const int r = bid * 4 + w;
    const int mb = r >> 7, lr = r & 127;
    const size_t base = (size_t)mb * 98304 + (lr >> 6) * 2048 + ((lr >> 4) & 3) * 512 + (lr & 15) * 8;
#pragma unroll
    for (int seg = 0; seg < 3; ++seg) {
      const int k = seg * 256 + l * 4;
      float4 v;
      if (seg == 0) v = *(const float4*)(x + (size_t)r * I_SZ + k);
      else          v = *(const float4*)(h + (size_t)r * H_SZ + (k - 256));
      const int kb = k >> 6, ks = (k >> 5) & 1, l4 = (k >> 3) & 3, e = k & 7;
      half4v o = {(_Float16)v.x, (_Float16)v.y, (_Float16)v.z, (_Float16)v.w};
      *(half4v*)(Af + base + kb * 8192 + ks * 4096 + l4 * 128 + e) = o;
    }
  } else if (bid < NA + NW) {
    const int r = (bid - NA) * 4 + w;   // packed W row = gate*512 + j
    const int g = r >> 9, j = r & 511;
    const int nb = j >> 5, jl = j & 31;
    const int cc = jl * 4 + g;          // tile col within 128-col block
    const int wc = cc >> 6, ni = (cc >> 4) & 3, l15 = cc & 15;
#pragma unroll
    for (int seg = 0; seg < 3; ++seg) {
      const int k = seg * 256 + l * 4;
      float4 v;
      if (seg == 0) v = *(const float4*)(Wx + (size_t)r * I_SZ + k);
      else          v = *(const float4*)(Wh + (size_t)r * H_SZ + (k - 256));
      const int kb = k >> 6, ks = (k >> 5) & 1, l4 = (k >> 3) & 3, e = k & 7;
      const int f = ((nb * 2 + wc) * 12 + kb) * 8 + ks * 4 + ni;
      half4v o = {(_Float16)v.x, (_Float16)v.y, (_Float16)v.z, (_Float16)v.w};
      *(half4v*)(Wf + (size_t)f * 512 + (l4 * 16 + l15) * 8 + e) = o;
    }
  } else {
#pragma unroll
    for (int q = 0; q < NG / 256; ++q) bs[q * 256 + t] = bx[q * 256 + t] + bh[q * 256 + t];
  }
}

// ---------------- main fused GEMM + LSTM epilogue (NO LDS / NO BARRIERS in K-loop) ----
// 128x128 block tile, 4 waves 2x2, 16x16x32 f16 MFMA.
// Both operands stream global->VGPR in fragment order (coalesced dwordx4, L1/L2-hot).
// Software pipeline at half-kb (K=32) granularity: 8 loads ahead of 16 MFMAs.
// __launch_bounds__(256,3): VGPR cap ~170 forces both buffers resident (round-4 lesson).
__global__ void __launch_bounds__(256, 3) lstm_gemm(const _Float16* __restrict__ Af,
                                                    const _Float16* __restrict__ Wf,
                                                    const float* __restrict__ bs,
                                                    const float* __restrict__ cIn,
                                                    float* __restrict__ outc,
                                                    float* __restrict__ outh) {
  __shared__ __align__(16) float Tbuf[4][2048];   // per-wave 8KB epilogue transpose

  const int t = threadIdx.x;
  const int lane = t & 63;
  const int wave = t >> 6;
  const int wr = wave >> 1, wc = wave & 1;
  const int l15 = lane & 15, l4 = lane >> 4;

  // XCD-aware: 128-bid chunk = 8 XCDs x 16 nb; same-XCD members share mb (A panel in one L2)
  const int bid = blockIdx.x;
  const int mb = (bid & 7) + (bid >> 7) * 8;
  const int nb = (bid >> 3) & 15;
  const int j0 = nb * 32;
  const int m0 = mb * 128;

  const _Float16* aPtr = Af + (size_t)mb * 98304 + wr * 2048 + lane * 8;
  const _Float16* wPtr = Wf + (size_t)(nb * 2 + wc) * 49152 + lane * 8;

  // init accumulators with bias
  f32x4 acc[4][4];
#pragma unroll
  for (int ni = 0; ni < 4; ++ni) {
    int tcol = wc * 64 + ni * 16 + l15;
    int gcol = (tcol & 3) * H_SZ + j0 + (tcol >> 2);
    float b = bs[gcol];
    f32x4 v = {b, b, b, b};
#pragma unroll
    for (int mi = 0; mi < 4; ++mi) acc[mi][ni] = v;
  }

  half8 bufA[8], bufB[8];   // [0..3]=A frags (mi), [4..7]=W frags (ni) for one K=32 stage

  auto loadStage = [&](int s, half8 (&buf)[8]) {
    const _Float16* ap = aPtr + (s >> 1) * 8192 + (s & 1) * 4096;
    const _Float16* wp = wPtr + (size_t)s * 2048;
#pragma unroll
    for (int mi = 0; mi < 4; ++mi) buf[mi] = *(const half8*)(ap + mi * 512);
#pragma unroll
    for (int ni = 0; ni < 4; ++ni) buf[4 + ni] = *(const half8*)(wp + ni * 512);
  };
  auto mfmaStage = [&](half8 (&buf)[8]) {
#pragma unroll
    for (int mi = 0; mi < 4; ++mi)
#pragma unroll
      for (int ni = 0; ni < 4; ++ni)
        acc[mi][ni] = __builtin_amdgcn_mfma_f32_16x16x32_f16(buf[mi], buf[4 + ni], acc[mi][ni], 0, 0, 0);
  };

  loadStage(0, bufA);
  for (int s = 0; s < 24; s += 2) {   // 24 stages of K=32
    loadStage(s + 1, bufB);
    mfmaStage(bufA);
    if (s + 2 < 24) loadStage(s + 2, bufA);
    mfmaStage(bufB);
  }

  // ---- epilogue: per-wave LDS transpose (stride 68 floats; no barrier, regions disjoint) ----
  float* T = Tbuf[wave];
#pragma unroll
  for (int mi = 0; mi < 4; ++mi) {
#pragma unroll
    for (int ni = 0; ni < 4; ++ni)
#pragma unroll
      for (int r = 0; r < 4; ++r)
        T[(l4 * 4 + r) * 68 + ni * 16 + l15] = acc[mi][ni][r];
#pragma unroll
    for (int orow = 0; orow < 4; ++orow) {
      int rloc = orow * 4 + l4;
      f32x4 gv = *(const f32x4*)(T + rloc * 68 + l15 * 4);
      int rowg = m0 + wr * 64 + mi * 16 + rloc;
      int jg = j0 + wc * 16 + l15;
      size_t off = (size_t)rowg * H_SZ + jg;
      float cv = cIn[off];
      float it = sigf(gv[0]);
      float ft = sigf(gv[1]);
      float ot = sigf(gv[2]);
      float tc = tanh_fast(gv[3]);
      float ct = ft * cv + it * tc;
      float ht = ot * tanh_fast(ct);
      outc[off] = ct;
      outh[off] = ht;
    }
  }
}

// ---------------- fallback (ws too small): plain fp32 ----------------
__global__ void __launch_bounds__(256) lstm_naive(const float* __restrict__ x,
                                                  const float* __restrict__ h,
                                                  const float* __restrict__ c,
                                                  const float* __restrict__ Wx,
                                                  const float* __restrict__ bx,
                                                  const float* __restrict__ Wh,
                                                  const float* __restrict__ bh,
                                                  float* __restrict__ outc,
                                                  float* __restrict__ outh) {
  int idx = blockIdx.x * 256 + threadIdx.x;
  int b = idx >> 9, j = idx & 511;
  float gi = bx[j] + bh[j];
  float gf = bx[H_SZ + j] + bh[H_SZ + j];
  float go = bx[2 * H_SZ + j] + bh[2 * H_SZ + j];
  float gc = bx[3 * H_SZ + j] + bh[3 * H_SZ + j];
  const float* xr = x + (size_t)b * I_SZ;
  for (int k = 0; k < I_SZ; ++k) {
    float xv = xr[k];
    gi += xv * Wx[(size_t)j * I_SZ + k];
    gf += xv * Wx[(size_t)(H_SZ + j) * I_SZ + k];
    go += xv * Wx[(size_t)(2 * H_SZ + j) * I_SZ + k];
    gc += xv * Wx[(size_t)(3 * H_SZ + j) * I_SZ + k];
  }
  const float* hr = h + (size_t)b * H_SZ;
  for (int k = 0; k < H_SZ; ++k) {
    float hv = hr[k];
    gi += hv * Wh[(size_t)j * H_SZ + k];
    gf += hv * Wh[(size_t)(H_SZ + j) * H_SZ + k];
    go += hv * Wh[(size_t)(2 * H_SZ + j) * H_SZ + k];
    gc += hv * Wh[(size_t)(3 * H_SZ + j) * H_SZ + k];
  }
  float it = sigf(gi), ft = sigf(gf), ot = sigf(go), tc = tanh_fast(gc);
  float ct = ft * c[idx] + it * tc;
  outc[idx] = ct;
  outh[idx] = ot * tanh_fast(ct);
}

extern "C" void kernel_launch(void* const* d_in, const int* in_sizes, int n_in,
                              void* d_out, int out_size, void* d_ws, size_t ws_size,
                              hipStream_t stream) {
  const float* x  = (const float*)d_in[0];
  const float* h  = (const float*)d_in[1];
  const float* c  = (const float*)d_in[2];
  const float* Wx = (const float*)d_in[3];
  const float* bx = (const float*)d_in[4];
  const float* Wh = (const float*)d_in[5];
  const float* bh = (const float*)d_in[6];
  float* outc = (float*)d_out;
  float* outh = outc + (size_t)B_SZ * H_SZ;

  const size_t szA = (size_t)B_SZ * K_SZ * sizeof(_Float16);
  const size_t szW = (size_t)NG * K_SZ * sizeof(_Float16);
  const size_t need = szA + szW + (size_t)NG * sizeof(float);

  if (ws_size < need) {
    lstm_naive<<<(B_SZ * H_SZ) / 256, 256, 0, stream>>>(x, h, c, Wx, bx, Wh, bh, outc, outh);
    return;
  }

  _Float16* Af = (_Float16*)d_ws;
  _Float16* Wf = (_Float16*)((char*)d_ws + szA);
  float* bs = (float*)((char*)d_ws + szA + szW);

  prepass<<<B_SZ / 4 + NG / 4 + 1, 256, 0, stream>>>(x, h, Wx, Wh, bx, bh, Af, Wf, bs);
  lstm_gemm<<<(B_SZ / 128) * (NG / 128), 256, 0, stream>>>(Af, Wf, bs, c, outc, outh);
}